// Round 1
// baseline (404.063 us; speedup 1.0000x reference)
//
#include <hip/hip_runtime.h>

typedef __bf16 bf16;
typedef __bf16 bf16x4_t __attribute__((ext_vector_type(4)));
typedef __bf16 bf16x8_t __attribute__((ext_vector_type(8)));
typedef float f32x4_t __attribute__((ext_vector_type(4)));

#define MFMA16(a, b, c) __builtin_amdgcn_mfma_f32_16x16x32_bf16(a, b, c, 0, 0, 0)

// ---------------- f32 -> bf16 cast (weights; redone every launch) ----------------
__global__ void cast_k(const float* __restrict__ s, bf16* __restrict__ d, int n) {
    int i = blockIdx.x * blockDim.x + threadIdx.x;
    int st = gridDim.x * blockDim.x;
    for (; i < n; i += st) d[i] = (bf16)s[i];
}

// ---------------- conditional layernorm -> xn bf16 ----------------
__global__ __launch_bounds__(256) void ln_k(const float* __restrict__ x,
                                            const int* __restrict__ gt,
                                            const float* __restrict__ tfg,
                                            const float* __restrict__ tfb,
                                            const float* __restrict__ tgg,
                                            const float* __restrict__ tgb,
                                            bf16* __restrict__ xn) {
    int t = blockIdx.x;
    int tid = threadIdx.x;
    const float* xr = x + (size_t)t * 512;
    float2 v = ((const float2*)xr)[tid];
    float s = v.x + v.y;
    float sq = v.x * v.x + v.y * v.y;
    for (int m = 1; m < 64; m <<= 1) {
        s += __shfl_xor(s, m, 64);
        sq += __shfl_xor(sq, m, 64);
    }
    __shared__ float ss[4], ssq[4];
    if ((tid & 63) == 0) { ss[tid >> 6] = s; ssq[tid >> 6] = sq; }
    __syncthreads();
    s = ss[0] + ss[1] + ss[2] + ss[3];
    sq = ssq[0] + ssq[1] + ssq[2] + ssq[3];
    float mean = s * (1.f / 512.f);
    float var = fmaxf(sq * (1.f / 512.f) - mean * mean, 0.f);
    float rstd = rsqrtf(var + 1e-5f);
    int g = gt[t];
    int d0 = tid * 2;
    float o0, o1;
    if (g == 0) {
        o0 = (v.x - mean) * rstd * tfg[d0] + tfb[d0];
        o1 = (v.y - mean) * rstd * tfg[d0 + 1] + tfb[d0 + 1];
    } else if (g == 1) {
        o0 = (v.x - mean) * rstd * tgg[d0] + tgb[d0];
        o1 = (v.y - mean) * rstd * tgg[d0 + 1] + tgb[d0 + 1];
    } else {
        o0 = v.x; o1 = v.y;
    }
    bf16* xo = xn + (size_t)t * 512 + d0;
    xo[0] = (bf16)o0;
    xo[1] = (bf16)o1;
}

// ---------------- NT GEMM: C[M,N] = A[M,K=512] * B[N,K=512]^T, bf16 MFMA ----------------
// 128x128 tile, BK=64, 256 threads (4 waves in 2x2), each wave 64x64 = 4x4 16x16 frags.
// EPI 0: +bias, scatter qkv (q scaled by 0.125*log2e, v transposed to [BH,64,S])
// EPI 1: +bias, +xn residual -> xr fp32 (xrf) + xr bf16 (p0)
// EPI 2: +bias, SiLU -> h bf16 (p0), N=256
template <int EPI>
__global__ __launch_bounds__(256) void gemm_k(const bf16* __restrict__ A,
                                              const bf16* __restrict__ B,
                                              const float* __restrict__ bias,
                                              bf16* __restrict__ p0,
                                              bf16* __restrict__ p1,
                                              bf16* __restrict__ p2,
                                              const bf16* __restrict__ xn,
                                              float* __restrict__ xrf) {
    int m0 = blockIdx.x * 128, n0 = blockIdx.y * 128;
    int tid = threadIdx.x;
    int lane = tid & 63, w = tid >> 6;
    int quad = lane >> 4, l15 = lane & 15;
    int wm = (w >> 1) * 64, wn = (w & 1) * 64;
    __shared__ bf16 As[128 * 72];
    __shared__ bf16 Bs[128 * 72];
    f32x4_t acc[4][4] = {};
    int srow = tid >> 3, ssub = tid & 7;
    const bf16* Ab = A + (size_t)(m0 + srow) * 512 + ssub * 8;
    const bf16* Bb = B + (size_t)(n0 + srow) * 512 + ssub * 8;
    uint4 pa[4], pb[4];
    auto gload = [&](int s) {
        int k0 = s * 64;
#pragma unroll
        for (int i = 0; i < 4; ++i) {
            pa[i] = *(const uint4*)(Ab + (size_t)(i * 32) * 512 + k0);
            pb[i] = *(const uint4*)(Bb + (size_t)(i * 32) * 512 + k0);
        }
    };
    auto sstore = [&]() {
#pragma unroll
        for (int i = 0; i < 4; ++i) {
            *(uint4*)&As[(i * 32 + srow) * 72 + ssub * 8] = pa[i];
            *(uint4*)&Bs[(i * 32 + srow) * 72 + ssub * 8] = pb[i];
        }
    };
    gload(0);
    sstore();
    for (int s = 0; s < 8; ++s) {
        __syncthreads();
        if (s < 7) gload(s + 1);
#pragma unroll
        for (int ks = 0; ks < 2; ++ks) {
            bf16x8_t af[4], bfr[4];
            int koff = ks * 32 + quad * 8;
#pragma unroll
            for (int mt = 0; mt < 4; ++mt)
                af[mt] = *(const bf16x8_t*)&As[(wm + mt * 16 + l15) * 72 + koff];
#pragma unroll
            for (int nt = 0; nt < 4; ++nt)
                bfr[nt] = *(const bf16x8_t*)&Bs[(wn + nt * 16 + l15) * 72 + koff];
#pragma unroll
            for (int mt = 0; mt < 4; ++mt)
#pragma unroll
                for (int nt = 0; nt < 4; ++nt)
                    acc[mt][nt] = MFMA16(af[mt], bfr[nt], acc[mt][nt]);
        }
        __syncthreads();
        if (s < 7) sstore();
    }
    // epilogue: C layout col=lane&15, row=quad*4+r (m89-verified)
#pragma unroll
    for (int mt = 0; mt < 4; ++mt) {
#pragma unroll
        for (int nt = 0; nt < 4; ++nt) {
            int gcol = n0 + wn + nt * 16 + l15;
            float bcol = bias[gcol];
#pragma unroll
            for (int r = 0; r < 4; ++r) {
                int grow = m0 + wm + mt * 16 + quad * 4 + r;
                float v = acc[mt][nt][r] + bcol;
                if constexpr (EPI == 0) {
                    int which = gcol >> 9;
                    int d = gcol & 511;
                    int hh = d >> 6, hd = d & 63;
                    int b = grow >> 11, ssi = grow & 2047;
                    size_t bh = (size_t)(b * 8 + hh);
                    if (which == 0) {
                        p0[(bh * 2048 + ssi) * 64 + hd] = (bf16)(v * 0.180336880111f); // 0.125*log2(e)
                    } else if (which == 1) {
                        p1[(bh * 2048 + ssi) * 64 + hd] = (bf16)v;
                    } else {
                        p2[(bh * 64 + hd) * 2048 + ssi] = (bf16)v; // V transposed
                    }
                } else if constexpr (EPI == 1) {
                    size_t idx = (size_t)grow * 512 + gcol;
                    float xv = v + (float)xn[idx];
                    xrf[idx] = xv;
                    p0[idx] = (bf16)xv;
                } else {
                    float sv = v / (1.f + __expf(-v)); // SiLU
                    p0[(size_t)grow * 256 + gcol] = (bf16)sv;
                }
            }
        }
    }
    (void)p1; (void)p2; (void)xn; (void)xrf;
}

// ---------------- flash attention: 128 q-rows/block, 64-wide kv tiles ----------------
// q,k: [BH, S, 64] bf16 (q pre-scaled by 0.125*log2e); vt: [BH, 64, S]; o: [B*S, 512]
__global__ __launch_bounds__(256) void attn_k(const bf16* __restrict__ q,
                                              const bf16* __restrict__ k,
                                              const bf16* __restrict__ vt,
                                              bf16* __restrict__ o) {
    int bh = blockIdx.y;
    int q0 = blockIdx.x * 128;
    int tid = threadIdx.x;
    int lane = tid & 63, w = tid >> 6;
    int quad = lane >> 4, l15 = lane & 15;
    __shared__ bf16 Ks[64 * 72];
    __shared__ bf16 Vs[64 * 72];
    __shared__ bf16 Ps[128 * 72];
    const bf16* qb = q + (size_t)bh * 2048 * 64;
    const bf16* kb = k + (size_t)bh * 2048 * 64;
    const bf16* vb = vt + (size_t)bh * 64 * 2048;
    bf16x8_t qf[2][2];
#pragma unroll
    for (int mt = 0; mt < 2; ++mt)
#pragma unroll
        for (int ks = 0; ks < 2; ++ks)
            qf[mt][ks] = *(const bf16x8_t*)(qb + (size_t)(q0 + w * 32 + mt * 16 + l15) * 64 + ks * 32 + quad * 8);
    f32x4_t oacc[2][4] = {};
    float mrow[2][4], lrow[2][4];
#pragma unroll
    for (int mt = 0; mt < 2; ++mt)
#pragma unroll
        for (int r = 0; r < 4; ++r) { mrow[mt][r] = -1e30f; lrow[mt][r] = 0.f; }
    int srow = tid >> 3, ssub = tid & 7;
    for (int kt = 0; kt < 32; ++kt) {
        int kbase = kt * 64;
        __syncthreads();
#pragma unroll
        for (int i = 0; i < 2; ++i) {
            int row = i * 32 + srow;
            *(uint4*)&Ks[row * 72 + ssub * 8] = *(const uint4*)(kb + (size_t)(kbase + row) * 64 + ssub * 8);
            *(uint4*)&Vs[row * 72 + ssub * 8] = *(const uint4*)(vb + (size_t)row * 2048 + kbase + ssub * 8);
        }
        __syncthreads();
        // scores: S = Q K^T (scale+log2e already folded into q)
        f32x4_t sacc[2][4] = {};
#pragma unroll
        for (int ks = 0; ks < 2; ++ks) {
            bf16x8_t kf[4];
            int koff = ks * 32 + quad * 8;
#pragma unroll
            for (int nt = 0; nt < 4; ++nt) kf[nt] = *(const bf16x8_t*)&Ks[(nt * 16 + l15) * 72 + koff];
#pragma unroll
            for (int mt = 0; mt < 2; ++mt)
#pragma unroll
                for (int nt = 0; nt < 4; ++nt)
                    sacc[mt][nt] = MFMA16(qf[mt][ks], kf[nt], sacc[mt][nt]);
        }
        // online softmax (exp2 domain), row stats via 16-lane shuffle reductions
#pragma unroll
        for (int mt = 0; mt < 2; ++mt) {
            float rm[4], rs[4], al[4];
#pragma unroll
            for (int r = 0; r < 4; ++r)
                rm[r] = fmaxf(fmaxf(sacc[mt][0][r], sacc[mt][1][r]), fmaxf(sacc[mt][2][r], sacc[mt][3][r]));
#pragma unroll
            for (int m = 1; m < 16; m <<= 1)
#pragma unroll
                for (int r = 0; r < 4; ++r) rm[r] = fmaxf(rm[r], __shfl_xor(rm[r], m, 64));
#pragma unroll
            for (int r = 0; r < 4; ++r) {
                float mn = fmaxf(mrow[mt][r], rm[r]);
                al[r] = exp2f(mrow[mt][r] - mn);
                mrow[mt][r] = mn;
            }
            float pv[4][4];
#pragma unroll
            for (int nt = 0; nt < 4; ++nt)
#pragma unroll
                for (int r = 0; r < 4; ++r) pv[nt][r] = exp2f(sacc[mt][nt][r] - mrow[mt][r]);
#pragma unroll
            for (int r = 0; r < 4; ++r) rs[r] = (pv[0][r] + pv[1][r]) + (pv[2][r] + pv[3][r]);
#pragma unroll
            for (int m = 1; m < 16; m <<= 1)
#pragma unroll
                for (int r = 0; r < 4; ++r) rs[r] += __shfl_xor(rs[r], m, 64);
#pragma unroll
            for (int r = 0; r < 4; ++r) lrow[mt][r] = lrow[mt][r] * al[r] + rs[r];
#pragma unroll
            for (int nt = 0; nt < 4; ++nt)
#pragma unroll
                for (int r = 0; r < 4; ++r) oacc[mt][nt][r] *= al[r];
            // P -> LDS in A-operand layout (wave-private rows; no barrier needed)
#pragma unroll
            for (int nt = 0; nt < 4; ++nt)
#pragma unroll
                for (int r = 0; r < 4; ++r)
                    Ps[(w * 32 + mt * 16 + quad * 4 + r) * 72 + nt * 16 + l15] = (bf16)pv[nt][r];
        }
        // O += P V
#pragma unroll
        for (int ks = 0; ks < 2; ++ks) {
            int koff = ks * 32 + quad * 8;
            bf16x8_t pf[2], vf[4];
#pragma unroll
            for (int mt = 0; mt < 2; ++mt) pf[mt] = *(const bf16x8_t*)&Ps[(w * 32 + mt * 16 + l15) * 72 + koff];
#pragma unroll
            for (int nt = 0; nt < 4; ++nt) vf[nt] = *(const bf16x8_t*)&Vs[(nt * 16 + l15) * 72 + koff];
#pragma unroll
            for (int mt = 0; mt < 2; ++mt)
#pragma unroll
                for (int nt = 0; nt < 4; ++nt)
                    oacc[mt][nt] = MFMA16(pf[mt], vf[nt], oacc[mt][nt]);
        }
    }
    // write O merged-head [token, 512] bf16
    int b = bh >> 3, hh = bh & 7;
#pragma unroll
    for (int mt = 0; mt < 2; ++mt)
#pragma unroll
        for (int r = 0; r < 4; ++r) {
            size_t t = (size_t)(b * 2048 + q0 + w * 32 + mt * 16 + quad * 4 + r);
            float inv = 1.f / lrow[mt][r];
#pragma unroll
            for (int nt = 0; nt < 4; ++nt)
                o[t * 512 + hh * 64 + nt * 16 + l15] = (bf16)(oacc[mt][nt][r] * inv);
        }
}

// ---------------- gate: strength = sigmoid(h . w2 + b2); out = xr * strength ----------------
__global__ __launch_bounds__(256) void gate_k(const bf16* __restrict__ h,
                                              const float* __restrict__ w2,
                                              const float* __restrict__ b2,
                                              const float* __restrict__ xrf,
                                              float* __restrict__ out) {
    int t = blockIdx.x * 4 + (threadIdx.x >> 6);
    int lane = threadIdx.x & 63;
    const bf16* hr = h + (size_t)t * 256;
    bf16x4_t hv = *(const bf16x4_t*)(hr + lane * 4);
    float4 wv = *(const float4*)(w2 + lane * 4);
    float dot = (float)hv[0] * wv.x + (float)hv[1] * wv.y + (float)hv[2] * wv.z + (float)hv[3] * wv.w;
    for (int m = 1; m < 64; m <<= 1) dot += __shfl_xor(dot, m, 64);
    float st = 1.f / (1.f + __expf(-(dot + b2[0])));
    const float4* x4 = (const float4*)(xrf + (size_t)t * 512);
    float4* o4 = (float4*)(out + (size_t)t * 512);
#pragma unroll
    for (int j = 0; j < 2; ++j) {
        float4 xv = x4[lane * 2 + j];
        float4 ov;
        ov.x = xv.x * st; ov.y = xv.y * st; ov.z = xv.z * st; ov.w = xv.w * st;
        o4[lane * 2 + j] = ov;
    }
}

extern "C" void kernel_launch(void* const* d_in, const int* in_sizes, int n_in,
                              void* d_out, int out_size, void* d_ws, size_t ws_size,
                              hipStream_t stream) {
    const float* x    = (const float*)d_in[0];
    const int*   gt   = (const int*)d_in[1];
    const float* tfg  = (const float*)d_in[2];
    const float* tfb  = (const float*)d_in[3];
    const float* tgg  = (const float*)d_in[4];
    const float* tgb  = (const float*)d_in[5];
    const float* Wqkv = (const float*)d_in[6];
    const float* bqkv = (const float*)d_in[7];
    const float* Wout = (const float*)d_in[8];
    const float* bout = (const float*)d_in[9];
    const float* W1   = (const float*)d_in[10];
    const float* b1   = (const float*)d_in[11];
    const float* w2   = (const float*)d_in[12];
    const float* b2   = (const float*)d_in[13];
    float* out = (float*)d_out;
    char* ws = (char*)d_ws;

    bf16*  xn  = (bf16*)(ws + 0);          //  8 MB  [8192,512]
    bf16*  q   = (bf16*)(ws + 8388608);    //  8 MB  [32,2048,64]
    bf16*  kk  = (bf16*)(ws + 16777216);   //  8 MB  [32,2048,64]
    bf16*  vt  = (bf16*)(ws + 25165824);   //  8 MB  [32,64,2048]
    bf16*  o   = (bf16*)(ws + 33554432);   //  8 MB  [8192,512]
    float* xrf = (float*)(ws + 41943040);  // 16 MB  [8192,512]
    bf16*  xrb = (bf16*)(ws + 58720256);   //  8 MB  [8192,512]
    bf16*  h   = (bf16*)(ws + 67108864);   //  4 MB  [8192,256]
    bf16*  wq  = (bf16*)(ws + 71303168);   //  1.5 MB [1536,512]
    bf16*  wo  = (bf16*)(ws + 72876032);   //  0.5 MB [512,512]
    bf16*  w1b = (bf16*)(ws + 73400320);   //  0.25 MB [256,512]

    cast_k<<<512, 256, 0, stream>>>(Wqkv, wq, 1536 * 512);
    cast_k<<<256, 256, 0, stream>>>(Wout, wo, 512 * 512);
    cast_k<<<128, 256, 0, stream>>>(W1, w1b, 256 * 512);
    ln_k<<<8192, 256, 0, stream>>>(x, gt, tfg, tfb, tgg, tgb, xn);
    gemm_k<0><<<dim3(64, 12), 256, 0, stream>>>(xn, wq, bqkv, q, kk, vt, nullptr, nullptr);
    attn_k<<<dim3(16, 32), 256, 0, stream>>>(q, kk, vt, o);
    gemm_k<1><<<dim3(64, 4), 256, 0, stream>>>(o, wo, bout, xrb, nullptr, nullptr, xn, xrf);
    gemm_k<2><<<dim3(64, 2), 256, 0, stream>>>(xrb, w1b, b1, h, nullptr, nullptr, nullptr, nullptr);
    gate_k<<<2048, 256, 0, stream>>>(h, w2, b2, xrf, out);
    (void)in_sizes; (void)n_in; (void)out_size; (void)ws_size;
}

// Round 3
// 342.524 us; speedup vs baseline: 1.1797x; 1.1797x over previous
//
#include <hip/hip_runtime.h>

typedef __bf16 bf16;
typedef __bf16 bf16x4_t __attribute__((ext_vector_type(4)));
typedef __bf16 bf16x8_t __attribute__((ext_vector_type(8)));
typedef float f32x4_t __attribute__((ext_vector_type(4)));

#define MFMA16(a, b, c) __builtin_amdgcn_mfma_f32_16x16x32_bf16(a, b, c, 0, 0, 0)

// ---------------- f32 -> bf16 cast of the 3 weight matrices, one kernel ----------------
__global__ void cast3_k(const float* __restrict__ a, const float* __restrict__ b,
                        const float* __restrict__ c, bf16* __restrict__ da,
                        bf16* __restrict__ db, bf16* __restrict__ dc) {
    int i = blockIdx.x * blockDim.x + threadIdx.x; // 0 .. 2304*512
    if (i < 786432) da[i] = (bf16)a[i];
    else if (i < 1048576) db[i - 786432] = (bf16)b[i - 786432];
    else if (i < 1179648) dc[i - 1048576] = (bf16)c[i - 1048576];
}

// ---------------- conditional layernorm -> xn bf16 ----------------
__global__ __launch_bounds__(256) void ln_k(const float* __restrict__ x,
                                            const int* __restrict__ gt,
                                            const float* __restrict__ tfg,
                                            const float* __restrict__ tfb,
                                            const float* __restrict__ tgg,
                                            const float* __restrict__ tgb,
                                            bf16* __restrict__ xn) {
    int t = blockIdx.x;
    int tid = threadIdx.x;
    const float* xr = x + (size_t)t * 512;
    float2 v = ((const float2*)xr)[tid];
    float s = v.x + v.y;
    float sq = v.x * v.x + v.y * v.y;
    for (int m = 1; m < 64; m <<= 1) {
        s += __shfl_xor(s, m, 64);
        sq += __shfl_xor(sq, m, 64);
    }
    __shared__ float ss[4], ssq[4];
    if ((tid & 63) == 0) { ss[tid >> 6] = s; ssq[tid >> 6] = sq; }
    __syncthreads();
    s = ss[0] + ss[1] + ss[2] + ss[3];
    sq = ssq[0] + ssq[1] + ssq[2] + ssq[3];
    float mean = s * (1.f / 512.f);
    float var = fmaxf(sq * (1.f / 512.f) - mean * mean, 0.f);
    float rstd = rsqrtf(var + 1e-5f);
    int g = gt[t];
    int d0 = tid * 2;
    float o0, o1;
    if (g == 0) {
        o0 = (v.x - mean) * rstd * tfg[d0] + tfb[d0];
        o1 = (v.y - mean) * rstd * tfg[d0 + 1] + tfb[d0 + 1];
    } else if (g == 1) {
        o0 = (v.x - mean) * rstd * tgg[d0] + tgb[d0];
        o1 = (v.y - mean) * rstd * tgg[d0 + 1] + tgb[d0 + 1];
    } else {
        o0 = v.x; o1 = v.y;
    }
    bf16* xo = xn + (size_t)t * 512 + d0;
    xo[0] = (bf16)o0;
    xo[1] = (bf16)o1;
}

// ---------------- NT GEMM: C[M,N] = A[M,K=512] * B[N,K=512]^T, bf16 MFMA ----------------
// EPI 0: +bias, scatter qkv (q scaled by 0.125*log2e, v transposed to [BH,64,S])
// EPI 1: +bias, +xn residual -> xr fp32 (xrf) + xr bf16 (p0)
// EPI 2: +bias, SiLU -> h bf16 (p0), N=256
template <int EPI>
__global__ __launch_bounds__(256) void gemm_k(const bf16* __restrict__ A,
                                              const bf16* __restrict__ B,
                                              const float* __restrict__ bias,
                                              bf16* __restrict__ p0,
                                              bf16* __restrict__ p1,
                                              bf16* __restrict__ p2,
                                              const bf16* __restrict__ xn,
                                              float* __restrict__ xrf) {
    int m0 = blockIdx.x * 128, n0 = blockIdx.y * 128;
    int tid = threadIdx.x;
    int lane = tid & 63, w = tid >> 6;
    int quad = lane >> 4, l15 = lane & 15;
    int wm = (w >> 1) * 64, wn = (w & 1) * 64;
    __shared__ bf16 As[128 * 72];
    __shared__ bf16 Bs[128 * 72];
    f32x4_t acc[4][4] = {};
    int srow = tid >> 3, ssub = tid & 7;
    const bf16* Ab = A + (size_t)(m0 + srow) * 512 + ssub * 8;
    const bf16* Bb = B + (size_t)(n0 + srow) * 512 + ssub * 8;
    uint4 pa[4], pb[4];
    auto gload = [&](int s) {
        int k0 = s * 64;
#pragma unroll
        for (int i = 0; i < 4; ++i) {
            pa[i] = *(const uint4*)(Ab + (size_t)(i * 32) * 512 + k0);
            pb[i] = *(const uint4*)(Bb + (size_t)(i * 32) * 512 + k0);
        }
    };
    auto sstore = [&]() {
#pragma unroll
        for (int i = 0; i < 4; ++i) {
            *(uint4*)&As[(i * 32 + srow) * 72 + ssub * 8] = pa[i];
            *(uint4*)&Bs[(i * 32 + srow) * 72 + ssub * 8] = pb[i];
        }
    };
    gload(0);
    sstore();
    for (int s = 0; s < 8; ++s) {
        __syncthreads();
        if (s < 7) gload(s + 1);
#pragma unroll
        for (int ks = 0; ks < 2; ++ks) {
            bf16x8_t af[4], bfr[4];
            int koff = ks * 32 + quad * 8;
#pragma unroll
            for (int mt = 0; mt < 4; ++mt)
                af[mt] = *(const bf16x8_t*)&As[(wm + mt * 16 + l15) * 72 + koff];
#pragma unroll
            for (int nt = 0; nt < 4; ++nt)
                bfr[nt] = *(const bf16x8_t*)&Bs[(wn + nt * 16 + l15) * 72 + koff];
#pragma unroll
            for (int mt = 0; mt < 4; ++mt)
#pragma unroll
                for (int nt = 0; nt < 4; ++nt)
                    acc[mt][nt] = MFMA16(af[mt], bfr[nt], acc[mt][nt]);
        }
        __syncthreads();
        if (s < 7) sstore();
    }
    // epilogue: C layout col=lane&15, row=quad*4+r (m89-verified)
#pragma unroll
    for (int mt = 0; mt < 4; ++mt) {
#pragma unroll
        for (int nt = 0; nt < 4; ++nt) {
            int gcol = n0 + wn + nt * 16 + l15;
            float bcol = bias[gcol];
#pragma unroll
            for (int r = 0; r < 4; ++r) {
                int grow = m0 + wm + mt * 16 + quad * 4 + r;
                float v = acc[mt][nt][r] + bcol;
                if constexpr (EPI == 0) {
                    int which = gcol >> 9;
                    int d = gcol & 511;
                    int hh = d >> 6, hd = d & 63;
                    int b = grow >> 11, ssi = grow & 2047;
                    size_t bh = (size_t)(b * 8 + hh);
                    if (which == 0) {
                        p0[(bh * 2048 + ssi) * 64 + hd] = (bf16)(v * 0.180336880111f); // 0.125*log2(e)
                    } else if (which == 1) {
                        p1[(bh * 2048 + ssi) * 64 + hd] = (bf16)v;
                    } else {
                        p2[(bh * 64 + hd) * 2048 + ssi] = (bf16)v; // V transposed
                    }
                } else if constexpr (EPI == 1) {
                    size_t idx = (size_t)grow * 512 + gcol;
                    float xv = v + (float)xn[idx];
                    xrf[idx] = xv;
                    p0[idx] = (bf16)xv;
                } else {
                    float sv = v / (1.f + __expf(-v)); // SiLU
                    p0[(size_t)grow * 256 + gcol] = (bf16)sv;
                }
            }
        }
    }
    (void)p1; (void)p2; (void)xn; (void)xrf;
}

// ---------------- flash attention, fixed-max exp2 softmax, 2-way KV split ----------------
// q,k: [BH,S,64] bf16 (q pre-scaled by 0.125*log2e); vt: [BH,64,S]
// pO: [split][BH,S,64] bf16 un-normalized; pL: [split][BH,S] f32 row sums
__global__ __launch_bounds__(256) void attn_k(const bf16* __restrict__ q,
                                              const bf16* __restrict__ k,
                                              const bf16* __restrict__ vt,
                                              bf16* __restrict__ pO,
                                              float* __restrict__ pL) {
    int bh = blockIdx.y;
    int q0 = blockIdx.x * 128;
    int sz = blockIdx.z; // kv split
    int tid = threadIdx.x;
    int lane = tid & 63, w = tid >> 6;
    int quad = lane >> 4, l15 = lane & 15;
    __shared__ bf16 Ks[64 * 72];
    __shared__ bf16 Vs[64 * 72];
    __shared__ bf16 Ps[128 * 72];
    const bf16* qb = q + (size_t)bh * 2048 * 64;
    const bf16* kb = k + (size_t)bh * 2048 * 64;
    const bf16* vb = vt + (size_t)bh * 64 * 2048;
    bf16x8_t qf[2][2];
#pragma unroll
    for (int mt = 0; mt < 2; ++mt)
#pragma unroll
        for (int ks = 0; ks < 2; ++ks)
            qf[mt][ks] = *(const bf16x8_t*)(qb + (size_t)(q0 + w * 32 + mt * 16 + l15) * 64 + ks * 32 + quad * 8);
    bf16x8_t ones;
#pragma unroll
    for (int i = 0; i < 8; ++i) ones[i] = (bf16)1.0f;
    f32x4_t oacc[2][4] = {};
    f32x4_t lacc[2] = {};
    int srow = tid >> 3, ssub = tid & 7;
    for (int kt = sz * 16; kt < sz * 16 + 16; ++kt) {
        int kbase = kt * 64;
        __syncthreads();
#pragma unroll
        for (int i = 0; i < 2; ++i) {
            int row = i * 32 + srow;
            *(uint4*)&Ks[row * 72 + ssub * 8] = *(const uint4*)(kb + (size_t)(kbase + row) * 64 + ssub * 8);
            *(uint4*)&Vs[row * 72 + ssub * 8] = *(const uint4*)(vb + (size_t)row * 2048 + kbase + ssub * 8);
        }
        __syncthreads();
        // S = Q K^T (log2-domain scale folded into q)
        f32x4_t sacc[2][4] = {};
#pragma unroll
        for (int ks = 0; ks < 2; ++ks) {
            bf16x8_t kf[4];
            int koff = ks * 32 + quad * 8;
#pragma unroll
            for (int nt = 0; nt < 4; ++nt) kf[nt] = *(const bf16x8_t*)&Ks[(nt * 16 + l15) * 72 + koff];
#pragma unroll
            for (int mt = 0; mt < 2; ++mt)
#pragma unroll
                for (int nt = 0; nt < 4; ++nt)
                    sacc[mt][nt] = MFMA16(qf[mt][ks], kf[nt], sacc[mt][nt]);
        }
        // P = exp2(S), straight to LDS in A-operand layout (wave-private rows)
#pragma unroll
        for (int mt = 0; mt < 2; ++mt)
#pragma unroll
            for (int nt = 0; nt < 4; ++nt)
#pragma unroll
                for (int r = 0; r < 4; ++r)
                    Ps[(w * 32 + mt * 16 + quad * 4 + r) * 72 + nt * 16 + l15] = (bf16)exp2f(sacc[mt][nt][r]);
        // O += P V ; l += P . 1 (row sums via MFMA with all-ones B)
#pragma unroll
        for (int ks = 0; ks < 2; ++ks) {
            int koff = ks * 32 + quad * 8;
            bf16x8_t pf[2], vf[4];
#pragma unroll
            for (int mt = 0; mt < 2; ++mt) pf[mt] = *(const bf16x8_t*)&Ps[(w * 32 + mt * 16 + l15) * 72 + koff];
#pragma unroll
            for (int nt = 0; nt < 4; ++nt) vf[nt] = *(const bf16x8_t*)&Vs[(nt * 16 + l15) * 72 + koff];
#pragma unroll
            for (int mt = 0; mt < 2; ++mt) {
#pragma unroll
                for (int nt = 0; nt < 4; ++nt)
                    oacc[mt][nt] = MFMA16(pf[mt], vf[nt], oacc[mt][nt]);
                lacc[mt] = MFMA16(pf[mt], ones, lacc[mt]);
            }
        }
    }
    // write partial O (un-normalized bf16) + row sums
    size_t obase = ((size_t)(sz * 32 + bh) * 2048 + q0);
#pragma unroll
    for (int mt = 0; mt < 2; ++mt)
#pragma unroll
        for (int r = 0; r < 4; ++r) {
            int row = w * 32 + mt * 16 + quad * 4 + r;
#pragma unroll
            for (int nt = 0; nt < 4; ++nt)
                pO[(obase + row) * 64 + nt * 16 + l15] = (bf16)oacc[mt][nt][r];
            if (l15 == 0) pL[obase + row] = lacc[mt][r];
        }
}

// ---------------- combine splits: o[t,512] = (O0+O1)/(l0+l1) ----------------
__global__ __launch_bounds__(256) void comb_k(const bf16* __restrict__ pO,
                                              const float* __restrict__ pL,
                                              bf16* __restrict__ o) {
    int i = blockIdx.x * 256 + threadIdx.x; // * 4 elems, total 32*2048*64
    int hd = (i & 15) * 4;
    int s = (i >> 4) & 2047;
    int bh = i >> 15;
    size_t r0 = (size_t)bh * 2048 + s;
    size_t r1 = (size_t)(32 + bh) * 2048 + s;
    float inv = 1.f / (pL[r0] + pL[r1]);
    bf16x4_t a = *(const bf16x4_t*)(pO + r0 * 64 + hd);
    bf16x4_t b = *(const bf16x4_t*)(pO + r1 * 64 + hd);
    int bb = bh >> 3, hh = bh & 7;
    bf16x4_t ov;
#pragma unroll
    for (int j = 0; j < 4; ++j) ov[j] = (bf16)(((float)a[j] + (float)b[j]) * inv);
    *(bf16x4_t*)(o + ((size_t)(bb * 2048 + s) * 512) + hh * 64 + hd) = ov;
}

// ---------------- gate: strength = sigmoid(h . w2 + b2); out = xr * strength ----------------
__global__ __launch_bounds__(256) void gate_k(const bf16* __restrict__ h,
                                              const float* __restrict__ w2,
                                              const float* __restrict__ b2,
                                              const float* __restrict__ xrf,
                                              float* __restrict__ out) {
    int t = blockIdx.x * 4 + (threadIdx.x >> 6);
    int lane = threadIdx.x & 63;
    const bf16* hr = h + (size_t)t * 256;
    bf16x4_t hv = *(const bf16x4_t*)(hr + lane * 4);
    float4 wv = *(const float4*)(w2 + lane * 4);
    float dot = (float)hv[0] * wv.x + (float)hv[1] * wv.y + (float)hv[2] * wv.z + (float)hv[3] * wv.w;
    for (int m = 1; m < 64; m <<= 1) dot += __shfl_xor(dot, m, 64);
    float st = 1.f / (1.f + __expf(-(dot + b2[0])));
    const float4* x4 = (const float4*)(xrf + (size_t)t * 512);
    float4* o4 = (float4*)(out + (size_t)t * 512);
#pragma unroll
    for (int j = 0; j < 2; ++j) {
        float4 xv = x4[lane * 2 + j];
        float4 ov;
        ov.x = xv.x * st; ov.y = xv.y * st; ov.z = xv.z * st; ov.w = xv.w * st;
        o4[lane * 2 + j] = ov;
    }
}

extern "C" void kernel_launch(void* const* d_in, const int* in_sizes, int n_in,
                              void* d_out, int out_size, void* d_ws, size_t ws_size,
                              hipStream_t stream) {
    const float* x    = (const float*)d_in[0];
    const int*   gt   = (const int*)d_in[1];
    const float* tfg  = (const float*)d_in[2];
    const float* tfb  = (const float*)d_in[3];
    const float* tgg  = (const float*)d_in[4];
    const float* tgb  = (const float*)d_in[5];
    const float* Wqkv = (const float*)d_in[6];
    const float* bqkv = (const float*)d_in[7];
    const float* Wout = (const float*)d_in[8];
    const float* bout = (const float*)d_in[9];
    const float* W1   = (const float*)d_in[10];
    const float* b1   = (const float*)d_in[11];
    const float* w2   = (const float*)d_in[12];
    const float* b2   = (const float*)d_in[13];
    float* out = (float*)d_out;
    char* ws = (char*)d_ws;

    const size_t MB = 1024 * 1024;
    // 0..48MB: activation scratch (aliased by liveness)
    bf16*  xn  = (bf16*)(ws + 0);              //  8 MB [8192,512]           live: ln..gemm1
    bf16*  q   = (bf16*)(ws + 8 * MB);         //  8 MB [32,2048,64]         live: gemm0..attn
    bf16*  o   = (bf16*)(ws + 8 * MB);         //  8 MB [8192,512]  (=q)     live: comb..gemm1
    bf16*  kk  = (bf16*)(ws + 16 * MB);        //  8 MB [32,2048,64]         live: gemm0..attn
    bf16*  vt  = (bf16*)(ws + 24 * MB);        //  8 MB [32,64,2048]         live: gemm0..attn
    float* xrf = (float*)(ws + 16 * MB);       // 16 MB [8192,512] (=kk,vt)  live: gemm1..gate
    bf16*  pO  = (bf16*)(ws + 32 * MB);        // 16 MB [2][32,2048,64]      live: attn..comb
    bf16*  xrb = (bf16*)(ws + 32 * MB);        //  8 MB [8192,512]  (=pO lo) live: gemm1..gemm2
    bf16*  h   = (bf16*)(ws + 40 * MB);        //  4 MB [8192,256]  (=pO hi) live: gemm2..gate
    // 48MB+: weights + row sums (symbolic offsets — R2 had literal-arithmetic aliasing here)
    bf16*  wq  = (bf16*)(ws + 48 * MB);                            // 1.5 MB [1536,512]
    bf16*  wo  = (bf16*)(ws + 48 * MB + 1536 * 512 * 2);           // 0.5 MB [512,512]
    bf16*  w1b = (bf16*)(ws + 48 * MB + (1536 + 512) * 512 * 2);   // 0.25 MB [256,512]
    float* pL  = (float*)(ws + 48 * MB + 2304 * 512 * 2);          // 0.5 MB [2][32,2048]

    cast3_k<<<4608, 256, 0, stream>>>(Wqkv, Wout, W1, wq, wo, w1b);
    ln_k<<<8192, 256, 0, stream>>>(x, gt, tfg, tfb, tgg, tgb, xn);
    gemm_k<0><<<dim3(64, 12), 256, 0, stream>>>(xn, wq, bqkv, q, kk, vt, nullptr, nullptr);
    attn_k<<<dim3(16, 32, 2), 256, 0, stream>>>(q, kk, vt, pO, pL);
    comb_k<<<4096, 256, 0, stream>>>(pO, pL, o);
    gemm_k<1><<<dim3(64, 4), 256, 0, stream>>>(o, wo, bout, xrb, nullptr, nullptr, xn, xrf);
    gemm_k<2><<<dim3(64, 2), 256, 0, stream>>>(xrb, w1b, b1, h, nullptr, nullptr, nullptr, nullptr);
    gate_k<<<2048, 256, 0, stream>>>(h, w2, b2, xrf, out);
    (void)in_sizes; (void)n_in; (void)out_size; (void)ws_size;
}